// Round 1
// baseline (11332.917 us; speedup 1.0000x reference)
//
#include <hip/hip_runtime.h>
#include <math.h>

#define NS 72
#define NS2 (NS*NS)          // 5184
#define NS3 (NS*NS*NS)       // 373248
#define CW 32
#define MZ 8
#define LALPHA 0.05f

__device__ __forceinline__ float leakyf(float v){ return v > 0.f ? v : LALPHA*v; }

// octant regions: x0, nx, y0, ny  (kz always [0,8))
__constant__ int c_RX0[8] = {0,64,0,64, 8,0,8,64};
__constant__ int c_RNX[8] = {8,8,8,8, 56,8,56,8};
__constant__ int c_RY0[8] = {0,0,64,64, 0,8,64,8};
__constant__ int c_RNY[8] = {8,8,8,8, 8,56,8,56};

// tw[t] = (cos(2*pi*t/72), sin(2*pi*t/72))
__global__ void k_tw(float2* tw){
  int t = threadIdx.x;
  if (t < NS){
    double th = (2.0*M_PI/72.0)*(double)t;
    tw[t] = make_float2((float)cos(th), (float)sin(th));
  }
}

// X[c][x][y][z] (32,72,72,72): fc0 on 64^3 region, zero pad elsewhere
__global__ void k_fc0(const float* __restrict__ yx, const float* __restrict__ yy,
                      const float* __restrict__ yz, const float* __restrict__ w,
                      const float* __restrict__ b, float* __restrict__ X){
  int idx = blockIdx.x*256 + threadIdx.x;          // 32*373248 = 46656*256
  int z = idx % NS; int t = idx / NS; int y = t % NS; t /= NS; int x = t % NS; int c = t / NS;
  float v = 0.f;
  if (x < 64 && y < 64 && z < 64){
    int p = (x*64 + y)*64 + z;
    float i0 = yx[p], i1 = yy[p], i2 = yz[p];
    float gx = (float)x*(1.f/63.f), gy = (float)y*(1.f/63.f), gz = (float)z*(1.f/63.f);
    v = b[c] + i0*w[0*32+c] + i1*w[1*32+c] + i2*w[2*32+c]
             + gx*w[3*32+c] + gy*w[4*32+c] + gz*w[5*32+c];
  }
  X[idx] = v;
}

// A[c][x][y][k] = sum_z X * e^{-2pi i z k/72}, k<8
__global__ void k_zdft(const float* __restrict__ X, float2* __restrict__ A, const float2* __restrict__ tw){
  __shared__ float2 stw[NS];
  int tid = threadIdx.x;
  if (tid < NS) stw[tid] = tw[tid];
  __syncthreads();
  int f = blockIdx.x*256 + tid;                    // (c,x,y): 165888 = 648*256
  const float* row = X + (size_t)f*NS;
  float ar[MZ], ai[MZ]; int tk[MZ];
  #pragma unroll
  for (int k=0;k<MZ;k++){ ar[k]=0.f; ai[k]=0.f; tk[k]=0; }
  for (int z=0; z<NS; z++){
    float v = row[z];
    #pragma unroll
    for (int k=0;k<MZ;k++){
      float2 w = stw[tk[k]];
      ar[k] += v*w.x;
      ai[k] -= v*w.y;
      tk[k] += k; if (tk[k] >= NS) tk[k] -= NS;
    }
  }
  float2* o = A + (size_t)f*MZ;
  #pragma unroll
  for (int k=0;k<MZ;k++) o[k] = make_float2(ar[k], ai[k]);
}

// B[c][x][ky][k] = sum_y A[c][x][y][k] * e^{-2pi i y ky/72}
__global__ void k_ydft(const float2* __restrict__ A, float2* __restrict__ B, const float2* __restrict__ tw){
  __shared__ float2 stw[NS];
  int tid = threadIdx.x;
  if (tid < NS) stw[tid] = tw[tid];
  __syncthreads();
  int f = blockIdx.x*256 + tid;
  int ky = f % NS; int cx = f / NS;
  const float2* in = A + (size_t)cx*NS*MZ;
  float ar[MZ], ai[MZ];
  #pragma unroll
  for (int k=0;k<MZ;k++){ ar[k]=0.f; ai[k]=0.f; }
  int t = 0;
  for (int y=0;y<NS;y++){
    float2 w = stw[t]; t += ky; if (t>=NS) t-=NS;
    const float2* iy = in + y*MZ;
    #pragma unroll
    for (int k=0;k<MZ;k++){
      float2 v = iy[k];
      ar[k] += v.x*w.x + v.y*w.y;
      ai[k] += v.y*w.x - v.x*w.y;
    }
  }
  float2* o = B + (size_t)f*MZ;
  #pragma unroll
  for (int k=0;k<MZ;k++) o[k] = make_float2(ar[k], ai[k]);
}

// C[c][kx][ky][k] = sum_x B[c][x][ky][k] * e^{-2pi i x kx/72}
__global__ void k_xdft(const float2* __restrict__ B, float2* __restrict__ C, const float2* __restrict__ tw){
  __shared__ float2 stw[NS];
  int tid = threadIdx.x;
  if (tid < NS) stw[tid] = tw[tid];
  __syncthreads();
  int f = blockIdx.x*256 + tid;
  int ky = f % NS; int t2 = f / NS; int kx = t2 % NS; int c = t2 / NS;
  const float2* in = B + ((size_t)c*NS2 + ky)*MZ;
  float ar[MZ], ai[MZ];
  #pragma unroll
  for (int k=0;k<MZ;k++){ ar[k]=0.f; ai[k]=0.f; }
  int t = 0;
  for (int x=0;x<NS;x++){
    float2 w = stw[t]; t += kx; if (t>=NS) t-=NS;
    const float2* ix = in + (size_t)x*NS*MZ;
    #pragma unroll
    for (int k=0;k<MZ;k++){
      float2 v = ix[k];
      ar[k] += v.x*w.x + v.y*w.y;
      ai[k] += v.y*w.x - v.x*w.y;
    }
  }
  float2* o = C + (size_t)f*MZ;
  #pragma unroll
  for (int k=0;k<MZ;k++) o[k] = make_float2(ar[k], ai[k]);
}

// frequency-domain 5^3 complex conv per octant region, pad=2 (zeros outside region)
__global__ __launch_bounds__(256) void k_freqconv(const float2* __restrict__ C, float2* __restrict__ D,
                                                  const float* __restrict__ W){
  __shared__ float4 WL[125*32];                    // [tap][co] -> (wRR,wRI,wIR,wII) = 64000 B
  int b = blockIdx.x;
  int r, base;
  if (b < 64) { r = b >> 4; base = r << 4; }
  else        { r = 4 + (b-64)/112; base = 64 + (r-4)*112; }
  int posblk = b - base;
  int x0 = c_RX0[r], nx = c_RNX[r], y0 = c_RY0[r], ny = c_RNY[r];
  const float* wreg = W + (size_t)r*64*64*125;
  int tid = threadIdx.x;
  int pl   = tid & 31;
  int quad = tid >> 5;                             // co group: co = quad*4 + j
  int pos = posblk*32 + pl;
  int p3 = pos & 7;
  int p2 = (pos >> 3) % ny;
  int p1 = (pos >> 3) / ny;
  float ar[4] = {0,0,0,0}, ai[4] = {0,0,0,0};
  for (int ci=0; ci<32; ci++){
    __syncthreads();
    for (int e=tid; e<16000; e+=256){
      int t = e >> 7; int rem = e & 127; int co = rem >> 2; int q = rem & 3;
      int o = 2*co + (q>>1); int i = ci + 32*(q&1);
      ((float*)WL)[e] = wreg[((size_t)(o*64+i))*125 + t];
    }
    __syncthreads();
    const float2* Cc = C + (size_t)ci*NS2*MZ;
    for (int td=0; td<5; td++){
      int q1 = p1 + td - 2; if ((unsigned)q1 >= (unsigned)nx) continue;
      for (int th=0; th<5; th++){
        int q2 = p2 + th - 2; if ((unsigned)q2 >= (unsigned)ny) continue;
        const float2* Crow = Cc + (((size_t)(x0+q1)*NS + (y0+q2))*MZ);
        for (int tz=0; tz<5; tz++){
          int q3 = p3 + tz - 2; if ((unsigned)q3 >= 8u) continue;
          float2 v = Crow[q3];
          const float4* wrow = WL + (td*25+th*5+tz)*32 + quad*4;
          #pragma unroll
          for (int j=0;j<4;j++){
            float4 w = wrow[j];
            ar[j] += w.x*v.x + w.y*v.y;
            ai[j] += w.z*v.x + w.w*v.y;
          }
        }
      }
    }
  }
  int ox = x0+p1, oy = y0+p2;
  #pragma unroll
  for (int j=0;j<4;j++){
    int co = quad*4+j;
    D[(((size_t)co*NS + ox)*NS + oy)*MZ + p3] = make_float2(ar[j], ai[j]);
  }
}

// E[c][x][ky][k] = (1/72) sum_kx D[c][kx][ky][k] * e^{+2pi i kx x/72}  (D center zeroed)
__global__ void k_invx(const float2* __restrict__ D, float2* __restrict__ E, const float2* __restrict__ tw){
  __shared__ float2 stw[NS];
  int tid = threadIdx.x;
  if (tid < NS) stw[tid] = tw[tid];
  __syncthreads();
  int f = blockIdx.x*256 + tid;
  int ky = f % NS; int t2 = f / NS; int x = t2 % NS; int c = t2 / NS;
  const float2* in = D + ((size_t)c*NS2 + ky)*MZ;
  float ar[MZ], ai[MZ];
  #pragma unroll
  for (int k=0;k<MZ;k++){ ar[k]=0.f; ai[k]=0.f; }
  int t = 0;
  for (int kx=0;kx<NS;kx++){
    float2 w = stw[t]; t += x; if (t>=NS) t-=NS;
    const float2* ix = in + (size_t)kx*NS*MZ;
    #pragma unroll
    for (int k=0;k<MZ;k++){
      float2 v = ix[k];
      ar[k] += v.x*w.x - v.y*w.y;
      ai[k] += v.x*w.y + v.y*w.x;
    }
  }
  float2* o = E + (size_t)f*MZ;
  #pragma unroll
  for (int k=0;k<MZ;k++) o[k] = make_float2(ar[k]*(1.f/72.f), ai[k]*(1.f/72.f));
}

// F[c][x][y][k] = (1/72) sum_ky E[c][x][ky][k] * e^{+2pi i ky y/72}
__global__ void k_invy(const float2* __restrict__ E, float2* __restrict__ F, const float2* __restrict__ tw){
  __shared__ float2 stw[NS];
  int tid = threadIdx.x;
  if (tid < NS) stw[tid] = tw[tid];
  __syncthreads();
  int f = blockIdx.x*256 + tid;
  int y = f % NS; int t2 = f / NS; int x = t2 % NS; int c = t2 / NS;
  const float2* in = E + ((size_t)c*NS + x)*NS*MZ;
  float ar[MZ], ai[MZ];
  #pragma unroll
  for (int k=0;k<MZ;k++){ ar[k]=0.f; ai[k]=0.f; }
  int t = 0;
  for (int ky=0;ky<NS;ky++){
    float2 w = stw[t]; t += y; if (t>=NS) t-=NS;
    const float2* ik = in + ky*MZ;
    #pragma unroll
    for (int k=0;k<MZ;k++){
      float2 v = ik[k];
      ar[k] += v.x*w.x - v.y*w.y;
      ai[k] += v.x*w.y + v.y*w.x;
    }
  }
  float2* o = F + (size_t)f*MZ;
  #pragma unroll
  for (int k=0;k<MZ;k++) o[k] = make_float2(ar[k]*(1.f/72.f), ai[k]*(1.f/72.f));
}

// X1[c][x][y][z] = (1/72)[Re F0 + 2*sum_{k=1..7}(Re Fk cos - Im Fk sin)]
__global__ void k_invz(const float2* __restrict__ F, float* __restrict__ X1, const float2* __restrict__ tw){
  __shared__ float2 stw[NS];
  int tid = threadIdx.x;
  if (tid < NS) stw[tid] = tw[tid];
  __syncthreads();
  int f = blockIdx.x*256 + tid;                    // (c,x,y)
  float2 v[MZ];
  const float2* in = F + (size_t)f*MZ;
  #pragma unroll
  for (int k=0;k<MZ;k++) v[k] = in[k];
  float* o = X1 + (size_t)f*NS;
  int tk[MZ];
  #pragma unroll
  for (int k=0;k<MZ;k++) tk[k]=0;
  for (int z=0; z<NS; z++){
    float acc = v[0].x;
    #pragma unroll
    for (int k=1;k<MZ;k++){
      float2 w = stw[tk[k]];
      acc += 2.f*(v[k].x*w.x - v[k].y*w.y);
      tk[k] += k; if (tk[k] >= NS) tk[k] -= NS;
    }
    o[z] = acc*(1.f/72.f);
  }
}

// 3^3 conv, 32->32 ch, zero-pad 1; leaky fused (first conv of basic block)
__global__ void k_conv3(const float* __restrict__ IN, const float* __restrict__ W,
                        float* __restrict__ OUT){
  __shared__ float wl[32*27];
  int tid = threadIdx.x;
  int p = blockIdx.x*256 + tid;                    // 373248 = 1458*256
  int z = p % NS; int t = p / NS; int y = t % NS; int x = t / NS;
  float acc[32];
  #pragma unroll
  for (int co=0;co<32;co++) acc[co]=0.f;
  for (int ci=0; ci<32; ci++){
    __syncthreads();
    for (int e=tid; e<864; e+=256) wl[e] = W[(size_t)((e/27)*32+ci)*27 + (e%27)];
    __syncthreads();
    float in[27];
    const float* I = IN + (size_t)ci*NS3;
    #pragma unroll
    for (int dx=0;dx<3;dx++)
    #pragma unroll
    for (int dy=0;dy<3;dy++)
    #pragma unroll
    for (int dz=0;dz<3;dz++){
      int xx=x+dx-1, yy=y+dy-1, zz=z+dz-1;
      bool ok = (unsigned)xx<(unsigned)NS && (unsigned)yy<(unsigned)NS && (unsigned)zz<(unsigned)NS;
      in[(dx*3+dy)*3+dz] = ok ? I[((size_t)xx*NS+yy)*NS+zz] : 0.f;
    }
    #pragma unroll
    for (int co=0;co<32;co++){
      float a = acc[co];
      #pragma unroll
      for (int tt=0;tt<27;tt++) a += in[tt]*wl[co*27+tt];
      acc[co]=a;
    }
  }
  #pragma unroll
  for (int co=0;co<32;co++) OUT[(size_t)co*NS3 + p] = leakyf(acc[co]);
}

// second conv + residual (x1 + x2 + x) + optional leaky, in-place on X
__global__ void k_conv3_fuse(const float* __restrict__ H, const float* __restrict__ W,
                             const float* __restrict__ X1, float* __restrict__ X, int do_leaky){
  __shared__ float wl[32*27];
  int tid = threadIdx.x;
  int p = blockIdx.x*256 + tid;
  int z = p % NS; int t = p / NS; int y = t % NS; int x = t / NS;
  float acc[32];
  #pragma unroll
  for (int co=0;co<32;co++) acc[co]=0.f;
  for (int ci=0; ci<32; ci++){
    __syncthreads();
    for (int e=tid; e<864; e+=256) wl[e] = W[(size_t)((e/27)*32+ci)*27 + (e%27)];
    __syncthreads();
    float in[27];
    const float* I = H + (size_t)ci*NS3;
    #pragma unroll
    for (int dx=0;dx<3;dx++)
    #pragma unroll
    for (int dy=0;dy<3;dy++)
    #pragma unroll
    for (int dz=0;dz<3;dz++){
      int xx=x+dx-1, yy=y+dy-1, zz=z+dz-1;
      bool ok = (unsigned)xx<(unsigned)NS && (unsigned)yy<(unsigned)NS && (unsigned)zz<(unsigned)NS;
      in[(dx*3+dy)*3+dz] = ok ? I[((size_t)xx*NS+yy)*NS+zz] : 0.f;
    }
    #pragma unroll
    for (int co=0;co<32;co++){
      float a = acc[co];
      #pragma unroll
      for (int tt=0;tt<27;tt++) a += in[tt]*wl[co*27+tt];
      acc[co]=a;
    }
  }
  #pragma unroll
  for (int co=0;co<32;co++){
    size_t idx = (size_t)co*NS3 + p;
    float v = acc[co] + X1[idx] + X[idx];
    if (do_leaky) v = leakyf(v);
    X[idx] = v;
  }
}

// crop to 64^3, fc1 (32->128) + leaky + fc2 (128->6)
__global__ void k_head(const float* __restrict__ X, const float* __restrict__ w1, const float* __restrict__ b1,
                       const float* __restrict__ w2, const float* __restrict__ b2, float* __restrict__ out){
  __shared__ float s1[32*128];
  __shared__ float sb1[128];
  __shared__ float s2[128*6];
  __shared__ float sb2[6];
  int tid = threadIdx.x;
  for (int e=tid;e<4096;e+=256) s1[e]=w1[e];
  if (tid<128) sb1[tid]=b1[tid];
  for (int e=tid;e<768;e+=256) s2[e]=w2[e];
  if (tid<6) sb2[tid]=b2[tid];
  __syncthreads();
  int p = blockIdx.x*256 + tid;                    // 262144 = 1024*256
  int z = p % 64; int t = p / 64; int y = t % 64; int x = t / 64;
  size_t q = ((size_t)x*NS + y)*NS + z;
  float xin[32];
  #pragma unroll
  for (int c=0;c<32;c++) xin[c] = X[(size_t)c*NS3 + q];
  float acc[6];
  #pragma unroll
  for (int o=0;o<6;o++) acc[o]=sb2[o];
  for (int j=0;j<128;j++){
    float h = sb1[j];
    #pragma unroll
    for (int c=0;c<32;c++) h += xin[c]*s1[c*128+j];
    h = leakyf(h);
    #pragma unroll
    for (int o=0;o<6;o++) acc[o] += h*s2[j*6+o];
  }
  float* O = out + (size_t)p*6;
  #pragma unroll
  for (int o=0;o<6;o++) O[o]=acc[o];
}

extern "C" void kernel_launch(void* const* d_in, const int* in_sizes, int n_in,
                              void* d_out, int out_size, void* d_ws, size_t ws_size,
                              hipStream_t stream) {
  const float* yeex = (const float*)d_in[0];
  const float* yeey = (const float*)d_in[1];
  const float* yeez = (const float*)d_in[2];
  const float* fc0w = (const float*)d_in[3];
  const float* fc0b = (const float*)d_in[4];
  const float* specw= (const float*)d_in[5];
  const float* bw1  = (const float*)d_in[6];
  const float* bw2  = (const float*)d_in[7];
  const float* fc1w = (const float*)d_in[8];
  const float* fc1b = (const float*)d_in[9];
  const float* fc2w = (const float*)d_in[10];
  const float* fc2b = (const float*)d_in[11];
  float* out = (float*)d_out;
  float* ws  = (float*)d_ws;

  float*  X  = ws;                                  // 11943936 floats
  float*  X1 = ws + 11943936;                       // 11943936
  float*  H  = ws + 23887872;                       // 11943936
  float2* A  = (float2*)(ws + 35831808);            // 2654208 cplx
  float2* B  = (float2*)(ws + 41140224);
  float2* Cf = (float2*)(ws + 46448640);
  float2* Df = (float2*)(ws + 51757056);
  float2* TW = (float2*)(ws + 57065472);            // 72 cplx
  // total ~228.3 MB of d_ws

  k_tw<<<1,128,0,stream>>>(TW);
  k_fc0<<<46656,256,0,stream>>>(yeex,yeey,yeez,fc0w,fc0b,X);
  for (int i=0;i<4;i++){
    k_zdft<<<648,256,0,stream>>>(X, A, TW);
    k_ydft<<<648,256,0,stream>>>(A, B, TW);
    k_xdft<<<648,256,0,stream>>>(B, Cf, TW);
    hipMemsetAsync(Df, 0, (size_t)5308416*4, stream);
    k_freqconv<<<512,256,0,stream>>>(Cf, Df, specw + (size_t)i*8*64*64*125);
    k_invx<<<648,256,0,stream>>>(Df, A, TW);
    k_invy<<<648,256,0,stream>>>(A, B, TW);
    k_invz<<<648,256,0,stream>>>(B, X1, TW);
    k_conv3<<<1458,256,0,stream>>>(X, bw1 + (size_t)i*27648, H);
    k_conv3_fuse<<<1458,256,0,stream>>>(H, bw2 + (size_t)i*27648, X1, X, (i<3)?1:0);
  }
  k_head<<<1024,256,0,stream>>>(X, fc1w, fc1b, fc2w, fc2b, out);
}

// Round 2
// 10092.275 us; speedup vs baseline: 1.1229x; 1.1229x over previous
//
#include <hip/hip_runtime.h>
#include <math.h>

#define NS 72
#define NS2 (NS*NS)          // 5184
#define NS3 (NS*NS*NS)       // 373248
#define CW 32
#define MZ 8
#define LALPHA 0.05f

__device__ __forceinline__ float leakyf(float v){ return v > 0.f ? v : LALPHA*v; }

// octant regions: x0, nx, y0, ny  (kz always [0,8))
__constant__ int c_RX0[8] = {0,64,0,64, 8,0,8,64};
__constant__ int c_RNX[8] = {8,8,8,8, 56,8,56,8};
__constant__ int c_RY0[8] = {0,0,64,64, 0,8,64,8};
__constant__ int c_RNY[8] = {8,8,8,8, 8,56,8,56};

// tw[t] = (cos(2*pi*t/72), sin(2*pi*t/72))
__global__ void k_tw(float2* tw){
  int t = threadIdx.x;
  if (t < NS){
    double th = (2.0*M_PI/72.0)*(double)t;
    tw[t] = make_float2((float)cos(th), (float)sin(th));
  }
}

// X[c][x][y][z] (32,72,72,72): fc0 on 64^3 region, zero pad elsewhere
__global__ void k_fc0(const float* __restrict__ yx, const float* __restrict__ yy,
                      const float* __restrict__ yz, const float* __restrict__ w,
                      const float* __restrict__ b, float* __restrict__ X){
  int idx = blockIdx.x*256 + threadIdx.x;          // 32*373248 = 46656*256
  int z = idx % NS; int t = idx / NS; int y = t % NS; t /= NS; int x = t % NS; int c = t / NS;
  float v = 0.f;
  if (x < 64 && y < 64 && z < 64){
    int p = (x*64 + y)*64 + z;
    float i0 = yx[p], i1 = yy[p], i2 = yz[p];
    float gx = (float)x*(1.f/63.f), gy = (float)y*(1.f/63.f), gz = (float)z*(1.f/63.f);
    v = b[c] + i0*w[0*32+c] + i1*w[1*32+c] + i2*w[2*32+c]
             + gx*w[3*32+c] + gy*w[4*32+c] + gz*w[5*32+c];
  }
  X[idx] = v;
}

// A[c][x][y][k] = sum_z X * e^{-2pi i z k/72}, k<8
__global__ void k_zdft(const float* __restrict__ X, float2* __restrict__ A, const float2* __restrict__ tw){
  __shared__ float2 stw[NS];
  int tid = threadIdx.x;
  if (tid < NS) stw[tid] = tw[tid];
  __syncthreads();
  int f = blockIdx.x*256 + tid;                    // (c,x,y): 165888 = 648*256
  const float* row = X + (size_t)f*NS;
  float ar[MZ], ai[MZ]; int tk[MZ];
  #pragma unroll
  for (int k=0;k<MZ;k++){ ar[k]=0.f; ai[k]=0.f; tk[k]=0; }
  for (int z=0; z<NS; z++){
    float v = row[z];
    #pragma unroll
    for (int k=0;k<MZ;k++){
      float2 w = stw[tk[k]];
      ar[k] += v*w.x;
      ai[k] -= v*w.y;
      tk[k] += k; if (tk[k] >= NS) tk[k] -= NS;
    }
  }
  float2* o = A + (size_t)f*MZ;
  #pragma unroll
  for (int k=0;k<MZ;k++) o[k] = make_float2(ar[k], ai[k]);
}

// B[c][x][ky][k] = sum_y A[c][x][y][k] * e^{-2pi i y ky/72}
__global__ void k_ydft(const float2* __restrict__ A, float2* __restrict__ B, const float2* __restrict__ tw){
  __shared__ float2 stw[NS];
  int tid = threadIdx.x;
  if (tid < NS) stw[tid] = tw[tid];
  __syncthreads();
  int f = blockIdx.x*256 + tid;
  int ky = f % NS; int cx = f / NS;
  const float2* in = A + (size_t)cx*NS*MZ;
  float ar[MZ], ai[MZ];
  #pragma unroll
  for (int k=0;k<MZ;k++){ ar[k]=0.f; ai[k]=0.f; }
  int t = 0;
  for (int y=0;y<NS;y++){
    float2 w = stw[t]; t += ky; if (t>=NS) t-=NS;
    const float2* iy = in + y*MZ;
    #pragma unroll
    for (int k=0;k<MZ;k++){
      float2 v = iy[k];
      ar[k] += v.x*w.x + v.y*w.y;
      ai[k] += v.y*w.x - v.x*w.y;
    }
  }
  float2* o = B + (size_t)f*MZ;
  #pragma unroll
  for (int k=0;k<MZ;k++) o[k] = make_float2(ar[k], ai[k]);
}

// C[c][kx][ky][k] = sum_x B[c][x][ky][k] * e^{-2pi i x kx/72}
__global__ void k_xdft(const float2* __restrict__ B, float2* __restrict__ C, const float2* __restrict__ tw){
  __shared__ float2 stw[NS];
  int tid = threadIdx.x;
  if (tid < NS) stw[tid] = tw[tid];
  __syncthreads();
  int f = blockIdx.x*256 + tid;
  int ky = f % NS; int t2 = f / NS; int kx = t2 % NS; int c = t2 / NS;
  const float2* in = B + ((size_t)c*NS2 + ky)*MZ;
  float ar[MZ], ai[MZ];
  #pragma unroll
  for (int k=0;k<MZ;k++){ ar[k]=0.f; ai[k]=0.f; }
  int t = 0;
  for (int x=0;x<NS;x++){
    float2 w = stw[t]; t += kx; if (t>=NS) t-=NS;
    const float2* ix = in + (size_t)x*NS*MZ;
    #pragma unroll
    for (int k=0;k<MZ;k++){
      float2 v = ix[k];
      ar[k] += v.x*w.x + v.y*w.y;
      ai[k] += v.y*w.x - v.x*w.y;
    }
  }
  float2* o = C + (size_t)f*MZ;
  #pragma unroll
  for (int k=0;k<MZ;k++) o[k] = make_float2(ar[k], ai[k]);
}

// prepack spectral weights for one layer:
// Wp[((r*32+ci)*125 + t)*32 + co] = (w[2co][ci], w[2co][32+ci], w[2co+1][ci], w[2co+1][32+ci])[t]
__global__ void k_wpack(const float* __restrict__ W, float4* __restrict__ Wp){
  int e = blockIdx.x*256 + threadIdx.x;            // 8*32*125*32 = 1,024,000 = 4000*256
  int co = e & 31; int t2 = e >> 5;
  int t = t2 % 125; t2 /= 125;
  int ci = t2 & 31; int r = t2 >> 5;
  const float* wr = W + (size_t)r*64*64*125;
  Wp[e] = make_float4(
    wr[((size_t)((2*co  )*64 + ci   ))*125 + t],
    wr[((size_t)((2*co  )*64 + 32+ci))*125 + t],
    wr[((size_t)((2*co+1)*64 + ci   ))*125 + t],
    wr[((size_t)((2*co+1)*64 + 32+ci))*125 + t]);
}

// frequency-domain 5^3 complex conv per octant region, pad=2 (zeros outside region)
// grid: 512 blocks = 256 pos-tiles (2x4x8) x 2 co-halves; block: 4 waves,
// wave = 64 positions x 4 co-complex; weights via wave-uniform scalar loads.
__global__ __launch_bounds__(256,2) void k_freqconv2(const float2* __restrict__ C, float2* __restrict__ D,
                                                     const float4* __restrict__ Wp){
  __shared__ float2 Ct[6*8*12];                    // [i1][i2][i3], 576 float2 = 4.6 KB
  int b = blockIdx.x;
  int h = b & 1; int t = b >> 1;
  int r, tloc;
  if (t < 32){ r = t >> 3; tloc = t & 7; }
  else       { r = 4 + (t-32)/56; tloc = (t-32)%56; }
  int x0 = c_RX0[r], nx = c_RNX[r], y0 = c_RY0[r], ny = c_RNY[r];
  int n2 = ny >> 2;
  int P1 = (tloc / n2)*2, P2 = (tloc % n2)*4;
  int tid = threadIdx.x;
  int lane = tid & 63;
  int p3 = lane & 7, p2l = (lane>>3)&3, p1l = lane>>5;
  int co0 = __builtin_amdgcn_readfirstlane(h*16 + (tid>>6)*4);   // wave-uniform co base
  const float4* wbase = Wp + ((size_t)r*32*125)*32 + co0;
  float ar[4] = {0,0,0,0}, ai[4] = {0,0,0,0};
  for (int ci=0; ci<32; ci++){
    __syncthreads();
    const float2* Cc = C + (size_t)ci*NS2*MZ;
    for (int e=tid; e<576; e+=256){
      int i3 = e % 12; int tt = e / 12; int i2 = tt & 7; int i1 = tt >> 3;
      int q1 = P1 + i1 - 2, q2 = P2 + i2 - 2, q3 = i3 - 2;
      float2 v = make_float2(0.f, 0.f);
      if ((unsigned)q1 < (unsigned)nx && (unsigned)q2 < (unsigned)ny && (unsigned)q3 < 8u)
        v = Cc[(((size_t)(x0+q1))*NS + (y0+q2))*MZ + q3];
      Ct[e] = v;
    }
    __syncthreads();
    const float4* wci = wbase + (size_t)ci*125*32;
    for (int td=0; td<5; td++){
      for (int th=0; th<5; th++){
        const float2* cp = &Ct[((p1l+td)*8 + (p2l+th))*12 + p3];
        const float4* wt = wci + (td*25+th*5)*32;
        #pragma unroll
        for (int tz=0; tz<5; tz++){
          float2 v = cp[tz];
          float4 w0 = wt[tz*32+0];
          float4 w1 = wt[tz*32+1];
          float4 w2 = wt[tz*32+2];
          float4 w3 = wt[tz*32+3];
          ar[0] += w0.x*v.x + w0.y*v.y; ai[0] += w0.z*v.x + w0.w*v.y;
          ar[1] += w1.x*v.x + w1.y*v.y; ai[1] += w1.z*v.x + w1.w*v.y;
          ar[2] += w2.x*v.x + w2.y*v.y; ai[2] += w2.z*v.x + w2.w*v.y;
          ar[3] += w3.x*v.x + w3.y*v.y; ai[3] += w3.z*v.x + w3.w*v.y;
        }
      }
    }
  }
  int ox = x0 + P1 + p1l, oy = y0 + P2 + p2l;
  #pragma unroll
  for (int j=0;j<4;j++){
    int co = co0 + j;
    D[(((size_t)co*NS + ox)*NS + oy)*MZ + p3] = make_float2(ar[j], ai[j]);
  }
}

// E[c][x][ky][k] = (1/72) sum_kx D[c][kx][ky][k] * e^{+2pi i kx x/72}  (D gaps zeroed)
__global__ void k_invx(const float2* __restrict__ D, float2* __restrict__ E, const float2* __restrict__ tw){
  __shared__ float2 stw[NS];
  int tid = threadIdx.x;
  if (tid < NS) stw[tid] = tw[tid];
  __syncthreads();
  int f = blockIdx.x*256 + tid;
  int ky = f % NS; int t2 = f / NS; int x = t2 % NS; int c = t2 / NS;
  const float2* in = D + ((size_t)c*NS2 + ky)*MZ;
  float ar[MZ], ai[MZ];
  #pragma unroll
  for (int k=0;k<MZ;k++){ ar[k]=0.f; ai[k]=0.f; }
  int t = 0;
  for (int kx=0;kx<NS;kx++){
    float2 w = stw[t]; t += x; if (t>=NS) t-=NS;
    const float2* ix = in + (size_t)kx*NS*MZ;
    #pragma unroll
    for (int k=0;k<MZ;k++){
      float2 v = ix[k];
      ar[k] += v.x*w.x - v.y*w.y;
      ai[k] += v.x*w.y + v.y*w.x;
    }
  }
  float2* o = E + (size_t)f*MZ;
  #pragma unroll
  for (int k=0;k<MZ;k++) o[k] = make_float2(ar[k]*(1.f/72.f), ai[k]*(1.f/72.f));
}

// F[c][x][y][k] = (1/72) sum_ky E[c][x][ky][k] * e^{+2pi i ky y/72}
__global__ void k_invy(const float2* __restrict__ E, float2* __restrict__ F, const float2* __restrict__ tw){
  __shared__ float2 stw[NS];
  int tid = threadIdx.x;
  if (tid < NS) stw[tid] = tw[tid];
  __syncthreads();
  int f = blockIdx.x*256 + tid;
  int y = f % NS; int t2 = f / NS; int x = t2 % NS; int c = t2 / NS;
  const float2* in = E + ((size_t)c*NS + x)*NS*MZ;
  float ar[MZ], ai[MZ];
  #pragma unroll
  for (int k=0;k<MZ;k++){ ar[k]=0.f; ai[k]=0.f; }
  int t = 0;
  for (int ky=0;ky<NS;ky++){
    float2 w = stw[t]; t += y; if (t>=NS) t-=NS;
    const float2* ik = in + ky*MZ;
    #pragma unroll
    for (int k=0;k<MZ;k++){
      float2 v = ik[k];
      ar[k] += v.x*w.x - v.y*w.y;
      ai[k] += v.x*w.y + v.y*w.x;
    }
  }
  float2* o = F + (size_t)f*MZ;
  #pragma unroll
  for (int k=0;k<MZ;k++) o[k] = make_float2(ar[k]*(1.f/72.f), ai[k]*(1.f/72.f));
}

// X1[c][x][y][z] = (1/72)[Re F0 + 2*sum_{k=1..7}(Re Fk cos - Im Fk sin)]
__global__ void k_invz(const float2* __restrict__ F, float* __restrict__ X1, const float2* __restrict__ tw){
  __shared__ float2 stw[NS];
  int tid = threadIdx.x;
  if (tid < NS) stw[tid] = tw[tid];
  __syncthreads();
  int f = blockIdx.x*256 + tid;                    // (c,x,y)
  float2 v[MZ];
  const float2* in = F + (size_t)f*MZ;
  #pragma unroll
  for (int k=0;k<MZ;k++) v[k] = in[k];
  float* o = X1 + (size_t)f*NS;
  int tk[MZ];
  #pragma unroll
  for (int k=0;k<MZ;k++) tk[k]=0;
  for (int z=0; z<NS; z++){
    float acc = v[0].x;
    #pragma unroll
    for (int k=1;k<MZ;k++){
      float2 w = stw[tk[k]];
      acc += 2.f*(v[k].x*w.x - v[k].y*w.y);
      tk[k] += k; if (tk[k] >= NS) tk[k] -= NS;
    }
    o[z] = acc*(1.f/72.f);
  }
}

// 3^3 conv, 32->32 ch, zero-pad 1; leaky fused (first conv of basic block)
__global__ void k_conv3(const float* __restrict__ IN, const float* __restrict__ W,
                        float* __restrict__ OUT){
  __shared__ float wl[32*27];
  int tid = threadIdx.x;
  int p = blockIdx.x*256 + tid;                    // 373248 = 1458*256
  int z = p % NS; int t = p / NS; int y = t % NS; int x = t / NS;
  float acc[32];
  #pragma unroll
  for (int co=0;co<32;co++) acc[co]=0.f;
  for (int ci=0; ci<32; ci++){
    __syncthreads();
    for (int e=tid; e<864; e+=256) wl[e] = W[(size_t)((e/27)*32+ci)*27 + (e%27)];
    __syncthreads();
    float in[27];
    const float* I = IN + (size_t)ci*NS3;
    #pragma unroll
    for (int dx=0;dx<3;dx++)
    #pragma unroll
    for (int dy=0;dy<3;dy++)
    #pragma unroll
    for (int dz=0;dz<3;dz++){
      int xx=x+dx-1, yy=y+dy-1, zz=z+dz-1;
      bool ok = (unsigned)xx<(unsigned)NS && (unsigned)yy<(unsigned)NS && (unsigned)zz<(unsigned)NS;
      in[(dx*3+dy)*3+dz] = ok ? I[((size_t)xx*NS+yy)*NS+zz] : 0.f;
    }
    #pragma unroll
    for (int co=0;co<32;co++){
      float a = acc[co];
      #pragma unroll
      for (int tt=0;tt<27;tt++) a += in[tt]*wl[co*27+tt];
      acc[co]=a;
    }
  }
  #pragma unroll
  for (int co=0;co<32;co++) OUT[(size_t)co*NS3 + p] = leakyf(acc[co]);
}

// second conv + residual (x1 + x2 + x) + optional leaky, in-place on X
__global__ void k_conv3_fuse(const float* __restrict__ H, const float* __restrict__ W,
                             const float* __restrict__ X1, float* __restrict__ X, int do_leaky){
  __shared__ float wl[32*27];
  int tid = threadIdx.x;
  int p = blockIdx.x*256 + tid;
  int z = p % NS; int t = p / NS; int y = t % NS; int x = t / NS;
  float acc[32];
  #pragma unroll
  for (int co=0;co<32;co++) acc[co]=0.f;
  for (int ci=0; ci<32; ci++){
    __syncthreads();
    for (int e=tid; e<864; e+=256) wl[e] = W[(size_t)((e/27)*32+ci)*27 + (e%27)];
    __syncthreads();
    float in[27];
    const float* I = H + (size_t)ci*NS3;
    #pragma unroll
    for (int dx=0;dx<3;dx++)
    #pragma unroll
    for (int dy=0;dy<3;dy++)
    #pragma unroll
    for (int dz=0;dz<3;dz++){
      int xx=x+dx-1, yy=y+dy-1, zz=z+dz-1;
      bool ok = (unsigned)xx<(unsigned)NS && (unsigned)yy<(unsigned)NS && (unsigned)zz<(unsigned)NS;
      in[(dx*3+dy)*3+dz] = ok ? I[((size_t)xx*NS+yy)*NS+zz] : 0.f;
    }
    #pragma unroll
    for (int co=0;co<32;co++){
      float a = acc[co];
      #pragma unroll
      for (int tt=0;tt<27;tt++) a += in[tt]*wl[co*27+tt];
      acc[co]=a;
    }
  }
  #pragma unroll
  for (int co=0;co<32;co++){
    size_t idx = (size_t)co*NS3 + p;
    float v = acc[co] + X1[idx] + X[idx];
    if (do_leaky) v = leakyf(v);
    X[idx] = v;
  }
}

// crop to 64^3, fc1 (32->128) + leaky + fc2 (128->6)
__global__ void k_head(const float* __restrict__ X, const float* __restrict__ w1, const float* __restrict__ b1,
                       const float* __restrict__ w2, const float* __restrict__ b2, float* __restrict__ out){
  __shared__ float s1[32*128];
  __shared__ float sb1[128];
  __shared__ float s2[128*6];
  __shared__ float sb2[6];
  int tid = threadIdx.x;
  for (int e=tid;e<4096;e+=256) s1[e]=w1[e];
  if (tid<128) sb1[tid]=b1[tid];
  for (int e=tid;e<768;e+=256) s2[e]=w2[e];
  if (tid<6) sb2[tid]=b2[tid];
  __syncthreads();
  int p = blockIdx.x*256 + tid;                    // 262144 = 1024*256
  int z = p % 64; int t = p / 64; int y = t % 64; int x = t / 64;
  size_t q = ((size_t)x*NS + y)*NS + z;
  float xin[32];
  #pragma unroll
  for (int c=0;c<32;c++) xin[c] = X[(size_t)c*NS3 + q];
  float acc[6];
  #pragma unroll
  for (int o=0;o<6;o++) acc[o]=sb2[o];
  for (int j=0;j<128;j++){
    float h = sb1[j];
    #pragma unroll
    for (int c=0;c<32;c++) h += xin[c]*s1[c*128+j];
    h = leakyf(h);
    #pragma unroll
    for (int o=0;o<6;o++) acc[o] += h*s2[j*6+o];
  }
  float* O = out + (size_t)p*6;
  #pragma unroll
  for (int o=0;o<6;o++) O[o]=acc[o];
}

extern "C" void kernel_launch(void* const* d_in, const int* in_sizes, int n_in,
                              void* d_out, int out_size, void* d_ws, size_t ws_size,
                              hipStream_t stream) {
  const float* yeex = (const float*)d_in[0];
  const float* yeey = (const float*)d_in[1];
  const float* yeez = (const float*)d_in[2];
  const float* fc0w = (const float*)d_in[3];
  const float* fc0b = (const float*)d_in[4];
  const float* specw= (const float*)d_in[5];
  const float* bw1  = (const float*)d_in[6];
  const float* bw2  = (const float*)d_in[7];
  const float* fc1w = (const float*)d_in[8];
  const float* fc1b = (const float*)d_in[9];
  const float* fc2w = (const float*)d_in[10];
  const float* fc2b = (const float*)d_in[11];
  float* out = (float*)d_out;
  float* ws  = (float*)d_ws;

  float*  X  = ws;                                  // 11943936 floats
  float*  X1 = ws + 11943936;                       // 11943936
  float*  H  = ws + 23887872;                       // 11943936
  float2* A  = (float2*)(ws + 35831808);            // 2654208 cplx (21.2 MB)
  float2* B  = (float2*)(ws + 41140224);
  float2* Cf = (float2*)(ws + 46448640);
  float2* Df = (float2*)(ws + 51757056);
  float2* TW = (float2*)(ws + 57065472);            // 72 cplx
  float4* Wp = (float4*)A;                          // reuse A between xdft and invx (16.4 MB <= 21.2 MB)

  k_tw<<<1,128,0,stream>>>(TW);
  k_fc0<<<46656,256,0,stream>>>(yeex,yeey,yeez,fc0w,fc0b,X);
  for (int i=0;i<4;i++){
    k_zdft<<<648,256,0,stream>>>(X, A, TW);
    k_ydft<<<648,256,0,stream>>>(A, B, TW);
    k_xdft<<<648,256,0,stream>>>(B, Cf, TW);
    // A is now free until invx writes it: pack this layer's spectral weights into it
    k_wpack<<<4000,256,0,stream>>>(specw + (size_t)i*8*64*64*125, Wp);
    hipMemsetAsync(Df, 0, (size_t)5308416*4, stream);
    k_freqconv2<<<512,256,0,stream>>>(Cf, Df, Wp);
    k_invx<<<648,256,0,stream>>>(Df, A, TW);
    k_invy<<<648,256,0,stream>>>(A, B, TW);
    k_invz<<<648,256,0,stream>>>(B, X1, TW);
    k_conv3<<<1458,256,0,stream>>>(X, bw1 + (size_t)i*27648, H);
    k_conv3_fuse<<<1458,256,0,stream>>>(H, bw2 + (size_t)i*27648, X1, X, (i<3)?1:0);
  }
  k_head<<<1024,256,0,stream>>>(X, fc1w, fc1b, fc2w, fc2b, out);
}

// Round 3
// 6293.097 us; speedup vs baseline: 1.8008x; 1.6037x over previous
//
#include <hip/hip_runtime.h>
#include <math.h>

#define NS 72
#define NS2 (NS*NS)          // 5184
#define NS3 (NS*NS*NS)       // 373248
#define CW 32
#define MZ 8
#define LALPHA 0.05f

__device__ __forceinline__ float leakyf(float v){ return v > 0.f ? v : LALPHA*v; }

// octant regions: x0, nx, y0, ny  (kz always [0,8))
__constant__ int c_RX0[8] = {0,64,0,64, 8,0,8,64};
__constant__ int c_RNX[8] = {8,8,8,8, 56,8,56,8};
__constant__ int c_RY0[8] = {0,0,64,64, 0,8,64,8};
__constant__ int c_RNY[8] = {8,8,8,8, 8,56,8,56};

// tw[t] = (cos(2*pi*t/72), sin(2*pi*t/72))
__global__ void k_tw(float2* tw){
  int t = threadIdx.x;
  if (t < NS){
    double th = (2.0*M_PI/72.0)*(double)t;
    tw[t] = make_float2((float)cos(th), (float)sin(th));
  }
}

// X[c][x][y][z] (32,72,72,72): fc0 on 64^3 region, zero pad elsewhere
__global__ void k_fc0(const float* __restrict__ yx, const float* __restrict__ yy,
                      const float* __restrict__ yz, const float* __restrict__ w,
                      const float* __restrict__ b, float* __restrict__ X){
  int idx = blockIdx.x*256 + threadIdx.x;          // 32*373248 = 46656*256
  int z = idx % NS; int t = idx / NS; int y = t % NS; t /= NS; int x = t % NS; int c = t / NS;
  float v = 0.f;
  if (x < 64 && y < 64 && z < 64){
    int p = (x*64 + y)*64 + z;
    float i0 = yx[p], i1 = yy[p], i2 = yz[p];
    float gx = (float)x*(1.f/63.f), gy = (float)y*(1.f/63.f), gz = (float)z*(1.f/63.f);
    v = b[c] + i0*w[0*32+c] + i1*w[1*32+c] + i2*w[2*32+c]
             + gx*w[3*32+c] + gy*w[4*32+c] + gz*w[5*32+c];
  }
  X[idx] = v;
}

// A[c][x][y][k] = sum_z X * e^{-2pi i z k/72}, k<8
__global__ void k_zdft(const float* __restrict__ X, float2* __restrict__ A, const float2* __restrict__ tw){
  __shared__ float2 stw[NS];
  int tid = threadIdx.x;
  if (tid < NS) stw[tid] = tw[tid];
  __syncthreads();
  int f = blockIdx.x*256 + tid;                    // (c,x,y): 165888 = 648*256
  const float* row = X + (size_t)f*NS;
  float ar[MZ], ai[MZ]; int tk[MZ];
  #pragma unroll
  for (int k=0;k<MZ;k++){ ar[k]=0.f; ai[k]=0.f; tk[k]=0; }
  for (int z=0; z<NS; z++){
    float v = row[z];
    #pragma unroll
    for (int k=0;k<MZ;k++){
      float2 w = stw[tk[k]];
      ar[k] += v*w.x;
      ai[k] -= v*w.y;
      tk[k] += k; if (tk[k] >= NS) tk[k] -= NS;
    }
  }
  float2* o = A + (size_t)f*MZ;
  #pragma unroll
  for (int k=0;k<MZ;k++) o[k] = make_float2(ar[k], ai[k]);
}

// B[c][x][ky][k] = sum_y A[c][x][y][k] * e^{-2pi i y ky/72}
__global__ void k_ydft(const float2* __restrict__ A, float2* __restrict__ B, const float2* __restrict__ tw){
  __shared__ float2 stw[NS];
  int tid = threadIdx.x;
  if (tid < NS) stw[tid] = tw[tid];
  __syncthreads();
  int f = blockIdx.x*256 + tid;
  int ky = f % NS; int cx = f / NS;
  const float2* in = A + (size_t)cx*NS*MZ;
  float ar[MZ], ai[MZ];
  #pragma unroll
  for (int k=0;k<MZ;k++){ ar[k]=0.f; ai[k]=0.f; }
  int t = 0;
  for (int y=0;y<NS;y++){
    float2 w = stw[t]; t += ky; if (t>=NS) t-=NS;
    const float2* iy = in + y*MZ;
    #pragma unroll
    for (int k=0;k<MZ;k++){
      float2 v = iy[k];
      ar[k] += v.x*w.x + v.y*w.y;
      ai[k] += v.y*w.x - v.x*w.y;
    }
  }
  float2* o = B + (size_t)f*MZ;
  #pragma unroll
  for (int k=0;k<MZ;k++) o[k] = make_float2(ar[k], ai[k]);
}

// C[c][kx][ky][k] = sum_x B[c][x][ky][k] * e^{-2pi i x kx/72}
__global__ void k_xdft(const float2* __restrict__ B, float2* __restrict__ C, const float2* __restrict__ tw){
  __shared__ float2 stw[NS];
  int tid = threadIdx.x;
  if (tid < NS) stw[tid] = tw[tid];
  __syncthreads();
  int f = blockIdx.x*256 + tid;
  int ky = f % NS; int t2 = f / NS; int kx = t2 % NS; int c = t2 / NS;
  const float2* in = B + ((size_t)c*NS2 + ky)*MZ;
  float ar[MZ], ai[MZ];
  #pragma unroll
  for (int k=0;k<MZ;k++){ ar[k]=0.f; ai[k]=0.f; }
  int t = 0;
  for (int x=0;x<NS;x++){
    float2 w = stw[t]; t += kx; if (t>=NS) t-=NS;
    const float2* ix = in + (size_t)x*NS*MZ;
    #pragma unroll
    for (int k=0;k<MZ;k++){
      float2 v = ix[k];
      ar[k] += v.x*w.x + v.y*w.y;
      ai[k] += v.y*w.x - v.x*w.y;
    }
  }
  float2* o = C + (size_t)f*MZ;
  #pragma unroll
  for (int k=0;k<MZ;k++) o[k] = make_float2(ar[k], ai[k]);
}

// prepack spectral weights for one layer into [r][cp][ci][tap][j] float4, co = cp*2+j
// float4 = (wRR, wRI, wIR, wII)
__global__ void k_wpack2(const float* __restrict__ W, float4* __restrict__ Wp){
  int e = blockIdx.x*256 + threadIdx.x;            // 8*16*32*125*2 = 1,024,000 = 4000*256
  int j = e & 1; int t2 = e >> 1;
  int t = t2 % 125; t2 /= 125;
  int ci = t2 & 31; t2 >>= 5;
  int cp = t2 & 15; int r = t2 >> 4;
  int co = cp*2 + j;
  const float* wr = W + (size_t)r*64*64*125;
  Wp[e] = make_float4(
    wr[((size_t)((2*co  )*64 + ci   ))*125 + t],
    wr[((size_t)((2*co  )*64 + 32+ci))*125 + t],
    wr[((size_t)((2*co+1)*64 + ci   ))*125 + t],
    wr[((size_t)((2*co+1)*64 + 32+ci))*125 + t]);
}

// frequency-domain 5^3 conv, one wave per block: 64 positions (2x4x8) x 2 co.
// 4096 blocks = 256 pos-tiles x 16 co-pairs. Register-double-buffered Ct prefetch,
// wave-synchronous (no barriers), weights via contiguous scalar stream.
__global__ __launch_bounds__(64) void k_freqconv3(const float2* __restrict__ C, float2* __restrict__ D,
                                                  const float4* __restrict__ Wp){
  __shared__ float2 Ct[576];                       // [i1=6][i2=8][i3=12], 4.6 KB
  int b = blockIdx.x;
  int cp = b & 15; int t = b >> 4;                 // t in [0,256)
  int r, tloc;
  if (t < 32){ r = t >> 3; tloc = t & 7; }
  else       { r = 4 + (t-32)/56; tloc = (t-32)%56; }
  int x0 = c_RX0[r], nx = c_RNX[r], y0 = c_RY0[r], ny = c_RNY[r];
  int n2 = ny >> 2;
  int P1 = (tloc / n2)*2, P2 = (tloc % n2)*4;
  int tid = threadIdx.x;
  int p3 = tid & 7, p2l = (tid>>3)&3, p1l = tid>>5;
  // precompute the 9 staged-element sources for this lane
  int voff[9]; bool val[9];
  #pragma unroll
  for (int k=0;k<9;k++){
    int e = tid + 64*k;
    int i3 = e % 12; int i2 = (e/12)&7; int i1 = e/96;
    int q1 = P1 + i1 - 2, q2 = P2 + i2 - 2, q3 = i3 - 2;
    bool v = (unsigned)q1 < (unsigned)nx && (unsigned)q2 < (unsigned)ny && (unsigned)q3 < 8u;
    val[k] = v;
    voff[k] = v ? (((x0+q1)*NS + (y0+q2))*MZ + q3) : 0;
  }
  const float4* wb = Wp + (size_t)(r*16+cp)*8000;  // 32ci*125tap*2
  float ar[2] = {0,0}, ai[2] = {0,0};
  float2 pf[9];
  #pragma unroll
  for (int k=0;k<9;k++) pf[k] = val[k] ? C[voff[k]] : make_float2(0.f,0.f);
  for (int ci=0; ci<32; ci++){
    #pragma unroll
    for (int k=0;k<9;k++) Ct[tid + 64*k] = pf[k];
    if (ci < 31){
      const float2* Cn = C + (size_t)(ci+1)*NS2*MZ;
      #pragma unroll
      for (int k=0;k<9;k++) pf[k] = val[k] ? Cn[voff[k]] : make_float2(0.f,0.f);
    }
    const float4* wci = wb + ci*250;
    for (int td=0; td<5; td++){
      for (int th=0; th<5; th++){
        const float2* cpt = &Ct[((p1l+td)*8 + (p2l+th))*12 + p3];
        const float4* wt = wci + (td*25+th*5)*2;
        #pragma unroll
        for (int tz=0; tz<5; tz++){
          float2 v = cpt[tz];
          float4 w0 = wt[tz*2+0];
          float4 w1 = wt[tz*2+1];
          ar[0] += w0.x*v.x + w0.y*v.y; ai[0] += w0.z*v.x + w0.w*v.y;
          ar[1] += w1.x*v.x + w1.y*v.y; ai[1] += w1.z*v.x + w1.w*v.y;
        }
      }
    }
  }
  int ox = x0 + P1 + p1l, oy = y0 + P2 + p2l;
  int co0 = cp*2;
  D[(((size_t)co0*NS + ox)*NS + oy)*MZ + p3]     = make_float2(ar[0], ai[0]);
  D[(((size_t)(co0+1)*NS + ox)*NS + oy)*MZ + p3] = make_float2(ar[1], ai[1]);
}

// E[c][x][ky][k] = (1/72) sum_kx D[c][kx][ky][k] * e^{+2pi i kx x/72}  (D gaps zeroed)
__global__ void k_invx(const float2* __restrict__ D, float2* __restrict__ E, const float2* __restrict__ tw){
  __shared__ float2 stw[NS];
  int tid = threadIdx.x;
  if (tid < NS) stw[tid] = tw[tid];
  __syncthreads();
  int f = blockIdx.x*256 + tid;
  int ky = f % NS; int t2 = f / NS; int x = t2 % NS; int c = t2 / NS;
  const float2* in = D + ((size_t)c*NS2 + ky)*MZ;
  float ar[MZ], ai[MZ];
  #pragma unroll
  for (int k=0;k<MZ;k++){ ar[k]=0.f; ai[k]=0.f; }
  int t = 0;
  for (int kx=0;kx<NS;kx++){
    float2 w = stw[t]; t += x; if (t>=NS) t-=NS;
    const float2* ix = in + (size_t)kx*NS*MZ;
    #pragma unroll
    for (int k=0;k<MZ;k++){
      float2 v = ix[k];
      ar[k] += v.x*w.x - v.y*w.y;
      ai[k] += v.x*w.y + v.y*w.x;
    }
  }
  float2* o = E + (size_t)f*MZ;
  #pragma unroll
  for (int k=0;k<MZ;k++) o[k] = make_float2(ar[k]*(1.f/72.f), ai[k]*(1.f/72.f));
}

// F[c][x][y][k] = (1/72) sum_ky E[c][x][ky][k] * e^{+2pi i ky y/72}
__global__ void k_invy(const float2* __restrict__ E, float2* __restrict__ F, const float2* __restrict__ tw){
  __shared__ float2 stw[NS];
  int tid = threadIdx.x;
  if (tid < NS) stw[tid] = tw[tid];
  __syncthreads();
  int f = blockIdx.x*256 + tid;
  int y = f % NS; int t2 = f / NS; int x = t2 % NS; int c = t2 / NS;
  const float2* in = E + ((size_t)c*NS + x)*NS*MZ;
  float ar[MZ], ai[MZ];
  #pragma unroll
  for (int k=0;k<MZ;k++){ ar[k]=0.f; ai[k]=0.f; }
  int t = 0;
  for (int ky=0;ky<NS;ky++){
    float2 w = stw[t]; t += y; if (t>=NS) t-=NS;
    const float2* ik = in + ky*MZ;
    #pragma unroll
    for (int k=0;k<MZ;k++){
      float2 v = ik[k];
      ar[k] += v.x*w.x - v.y*w.y;
      ai[k] += v.x*w.y + v.y*w.x;
    }
  }
  float2* o = F + (size_t)f*MZ;
  #pragma unroll
  for (int k=0;k<MZ;k++) o[k] = make_float2(ar[k]*(1.f/72.f), ai[k]*(1.f/72.f));
}

// X1[c][x][y][z] = (1/72)[Re F0 + 2*sum_{k=1..7}(Re Fk cos - Im Fk sin)]
__global__ void k_invz(const float2* __restrict__ F, float* __restrict__ X1, const float2* __restrict__ tw){
  __shared__ float2 stw[NS];
  int tid = threadIdx.x;
  if (tid < NS) stw[tid] = tw[tid];
  __syncthreads();
  int f = blockIdx.x*256 + tid;                    // (c,x,y)
  float2 v[MZ];
  const float2* in = F + (size_t)f*MZ;
  #pragma unroll
  for (int k=0;k<MZ;k++) v[k] = in[k];
  float* o = X1 + (size_t)f*NS;
  int tk[MZ];
  #pragma unroll
  for (int k=0;k<MZ;k++) tk[k]=0;
  for (int z=0; z<NS; z++){
    float acc = v[0].x;
    #pragma unroll
    for (int k=1;k<MZ;k++){
      float2 w = stw[tk[k]];
      acc += 2.f*(v[k].x*w.x - v[k].y*w.y);
      tk[k] += k; if (tk[k] >= NS) tk[k] -= NS;
    }
    o[z] = acc*(1.f/72.f);
  }
}

// 3^3 conv, 32->32 ch, zero-pad 1, leaky fused; 4 z-positions per thread
__global__ __launch_bounds__(256,2) void k_conv3b(const float* __restrict__ IN, const float* __restrict__ W,
                                                  float* __restrict__ OUT){
  __shared__ float wl[864];
  int tid = threadIdx.x;
  int p = blockIdx.x*256 + tid;                    // 93312 = 5184 rows * 18 z-chunks
  bool active = p < 93312;
  int pc = active ? p : 0;
  int row = pc/18; int z0 = (pc%18)*4;
  int x = row / NS, y = row % NS;
  float acc[32][4];
  #pragma unroll
  for (int co=0;co<32;co++){ acc[co][0]=0.f; acc[co][1]=0.f; acc[co][2]=0.f; acc[co][3]=0.f; }
  for (int ci=0; ci<32; ci++){
    __syncthreads();
    for (int e=tid; e<864; e+=256) wl[e] = W[(size_t)((e/27)*32+ci)*27 + (e%27)];
    __syncthreads();
    float w6[9][6];
    #pragma unroll
    for (int dx=0;dx<3;dx++){
      #pragma unroll
      for (int dy=0;dy<3;dy++){
        int xx = x+dx-1, yy = y+dy-1;
        bool rowok = active && (unsigned)xx < (unsigned)NS && (unsigned)yy < (unsigned)NS;
        const float* I = IN + (size_t)ci*NS3 + ((size_t)(rowok?xx:0)*NS + (rowok?yy:0))*NS;
        #pragma unroll
        for (int e=0;e<6;e++){
          int zz = z0 + e - 1;
          w6[dx*3+dy][e] = (rowok && (unsigned)zz < (unsigned)NS) ? I[zz] : 0.f;
        }
      }
    }
    #pragma unroll
    for (int co=0;co<32;co++){
      #pragma unroll
      for (int t=0;t<27;t++){
        float wv = wl[co*27+t];
        int rr = t/3, dz = t%3;
        acc[co][0] += wv*w6[rr][dz+0];
        acc[co][1] += wv*w6[rr][dz+1];
        acc[co][2] += wv*w6[rr][dz+2];
        acc[co][3] += wv*w6[rr][dz+3];
      }
    }
  }
  if (active){
    #pragma unroll
    for (int co=0;co<32;co++){
      float4 o = make_float4(leakyf(acc[co][0]), leakyf(acc[co][1]), leakyf(acc[co][2]), leakyf(acc[co][3]));
      *(float4*)(OUT + (size_t)co*NS3 + (size_t)row*NS + z0) = o;
    }
  }
}

// second conv + residual (x1 + x2 + x) + optional leaky, in-place on X; 4 z per thread
__global__ __launch_bounds__(256,2) void k_conv3_fuse_b(const float* __restrict__ H, const float* __restrict__ W,
                                                        const float* __restrict__ X1, float* __restrict__ X, int do_leaky){
  __shared__ float wl[864];
  int tid = threadIdx.x;
  int p = blockIdx.x*256 + tid;
  bool active = p < 93312;
  int pc = active ? p : 0;
  int row = pc/18; int z0 = (pc%18)*4;
  int x = row / NS, y = row % NS;
  float acc[32][4];
  #pragma unroll
  for (int co=0;co<32;co++){ acc[co][0]=0.f; acc[co][1]=0.f; acc[co][2]=0.f; acc[co][3]=0.f; }
  for (int ci=0; ci<32; ci++){
    __syncthreads();
    for (int e=tid; e<864; e+=256) wl[e] = W[(size_t)((e/27)*32+ci)*27 + (e%27)];
    __syncthreads();
    float w6[9][6];
    #pragma unroll
    for (int dx=0;dx<3;dx++){
      #pragma unroll
      for (int dy=0;dy<3;dy++){
        int xx = x+dx-1, yy = y+dy-1;
        bool rowok = active && (unsigned)xx < (unsigned)NS && (unsigned)yy < (unsigned)NS;
        const float* I = H + (size_t)ci*NS3 + ((size_t)(rowok?xx:0)*NS + (rowok?yy:0))*NS;
        #pragma unroll
        for (int e=0;e<6;e++){
          int zz = z0 + e - 1;
          w6[dx*3+dy][e] = (rowok && (unsigned)zz < (unsigned)NS) ? I[zz] : 0.f;
        }
      }
    }
    #pragma unroll
    for (int co=0;co<32;co++){
      #pragma unroll
      for (int t=0;t<27;t++){
        float wv = wl[co*27+t];
        int rr = t/3, dz = t%3;
        acc[co][0] += wv*w6[rr][dz+0];
        acc[co][1] += wv*w6[rr][dz+1];
        acc[co][2] += wv*w6[rr][dz+2];
        acc[co][3] += wv*w6[rr][dz+3];
      }
    }
  }
  if (active){
    #pragma unroll
    for (int co=0;co<32;co++){
      size_t base = (size_t)co*NS3 + (size_t)row*NS + z0;
      float4 x1v = *(const float4*)(X1 + base);
      float4 xv  = *(const float4*)(X  + base);
      float4 o;
      o.x = acc[co][0] + x1v.x + xv.x;
      o.y = acc[co][1] + x1v.y + xv.y;
      o.z = acc[co][2] + x1v.z + xv.z;
      o.w = acc[co][3] + x1v.w + xv.w;
      if (do_leaky){ o.x=leakyf(o.x); o.y=leakyf(o.y); o.z=leakyf(o.z); o.w=leakyf(o.w); }
      *(float4*)(X + base) = o;
    }
  }
}

// crop to 64^3, fc1 (32->128) + leaky + fc2 (128->6)
__global__ void k_head(const float* __restrict__ X, const float* __restrict__ w1, const float* __restrict__ b1,
                       const float* __restrict__ w2, const float* __restrict__ b2, float* __restrict__ out){
  __shared__ float s1[32*128];
  __shared__ float sb1[128];
  __shared__ float s2[128*6];
  __shared__ float sb2[6];
  int tid = threadIdx.x;
  for (int e=tid;e<4096;e+=256) s1[e]=w1[e];
  if (tid<128) sb1[tid]=b1[tid];
  for (int e=tid;e<768;e+=256) s2[e]=w2[e];
  if (tid<6) sb2[tid]=b2[tid];
  __syncthreads();
  int p = blockIdx.x*256 + tid;                    // 262144 = 1024*256
  int z = p % 64; int t = p / 64; int y = t % 64; int x = t / 64;
  size_t q = ((size_t)x*NS + y)*NS + z;
  float xin[32];
  #pragma unroll
  for (int c=0;c<32;c++) xin[c] = X[(size_t)c*NS3 + q];
  float acc[6];
  #pragma unroll
  for (int o=0;o<6;o++) acc[o]=sb2[o];
  for (int j=0;j<128;j++){
    float h = sb1[j];
    #pragma unroll
    for (int c=0;c<32;c++) h += xin[c]*s1[c*128+j];
    h = leakyf(h);
    #pragma unroll
    for (int o=0;o<6;o++) acc[o] += h*s2[j*6+o];
  }
  float* O = out + (size_t)p*6;
  #pragma unroll
  for (int o=0;o<6;o++) O[o]=acc[o];
}

extern "C" void kernel_launch(void* const* d_in, const int* in_sizes, int n_in,
                              void* d_out, int out_size, void* d_ws, size_t ws_size,
                              hipStream_t stream) {
  const float* yeex = (const float*)d_in[0];
  const float* yeey = (const float*)d_in[1];
  const float* yeez = (const float*)d_in[2];
  const float* fc0w = (const float*)d_in[3];
  const float* fc0b = (const float*)d_in[4];
  const float* specw= (const float*)d_in[5];
  const float* bw1  = (const float*)d_in[6];
  const float* bw2  = (const float*)d_in[7];
  const float* fc1w = (const float*)d_in[8];
  const float* fc1b = (const float*)d_in[9];
  const float* fc2w = (const float*)d_in[10];
  const float* fc2b = (const float*)d_in[11];
  float* out = (float*)d_out;
  float* ws  = (float*)d_ws;

  float*  X  = ws;                                  // 11943936 floats
  float*  X1 = ws + 11943936;                       // 11943936
  float*  H  = ws + 23887872;                       // 11943936
  float2* A  = (float2*)(ws + 35831808);            // slot of 5308416 floats (21.2 MB)
  float2* B  = (float2*)(ws + 41140224);
  float2* Cf = (float2*)(ws + 46448640);
  float2* Df = (float2*)(ws + 51757056);
  float2* TW = (float2*)(ws + 57065472);            // 72 cplx
  float4* Wp = (float4*)A;                          // reuse A between ydft and invx (16.4 MB <= 21.2 MB)

  k_tw<<<1,128,0,stream>>>(TW);
  k_fc0<<<46656,256,0,stream>>>(yeex,yeey,yeez,fc0w,fc0b,X);
  for (int i=0;i<4;i++){
    k_zdft<<<648,256,0,stream>>>(X, A, TW);
    k_ydft<<<648,256,0,stream>>>(A, B, TW);
    k_xdft<<<648,256,0,stream>>>(B, Cf, TW);
    // A is free until invx writes it: pack this layer's spectral weights into it
    k_wpack2<<<4000,256,0,stream>>>(specw + (size_t)i*8*64*64*125, Wp);
    hipMemsetAsync(Df, 0, (size_t)1327104*8, stream);
    k_freqconv3<<<4096,64,0,stream>>>(Cf, Df, Wp);
    k_invx<<<648,256,0,stream>>>(Df, A, TW);
    k_invy<<<648,256,0,stream>>>(A, B, TW);
    k_invz<<<648,256,0,stream>>>(B, X1, TW);
    k_conv3b<<<365,256,0,stream>>>(X, bw1 + (size_t)i*27648, H);
    k_conv3_fuse_b<<<365,256,0,stream>>>(H, bw2 + (size_t)i*27648, X1, X, (i<3)?1:0);
  }
  k_head<<<1024,256,0,stream>>>(X, fc1w, fc1b, fc2w, fc2b, out);
}